// Round 25
// baseline (141.323 us; speedup 1.0000x reference)
//
#include <hip/hip_runtime.h>
#include <hip/hip_bf16.h>
#include <hip/hip_fp8.h>

// AttnBlock: B=8, C=512, N=2048, G=32.
// R25 = R24 with the S-GEMM batch-offset bug fixed: pass batch via sA=1048576
// (q8 per-batch stride), mOffB=0 — R24 passed mOffB=2048 which double-added the
// batch offset in MODE 2's b*sOut / b*sRes epilogue indexing -> OOB writes,
// zero rowsum for b>0, div-by-zero -> NaN.
// Algebra (unchanged from R24): k and v projections eliminated:
//   S = hT*(Wq^T Wk)*hT^T  -> q' = hT*MqkT (N=512), S reuses hT as B operand.
//   out = (Wp Wv)*(P*h)^T / rowsum + (Wp bv + bp) + x;  R = P*h8 (natural h).
//   M matrices scaled x16 into fp8 (exact power-of-2, folded into epilogues).
// Keeps: m97 128x128 MX core (scale=1.0), fused exp+rowsum, /rowsum, T2 swizzle,
// batch->XCD pinning.

typedef __attribute__((ext_vector_type(8))) short short8;
typedef __attribute__((ext_vector_type(4))) float f32x4;
typedef __attribute__((ext_vector_type(8))) int i32x8;
typedef __attribute__((ext_vector_type(4))) int i32x4;
typedef unsigned short u16;
typedef unsigned char u8;
typedef unsigned int u32;

#define BK 64

__device__ __forceinline__ u16 f2bf(float f) {
  __hip_bfloat16 h = __float2bfloat16(f);
  return __builtin_bit_cast(u16, h);
}
__device__ __forceinline__ float bf2f(u16 u) {
  return __uint_as_float(((u32)u) << 16);
}
__device__ __forceinline__ u8 f2fp8(float f) {
  __hip_fp8_e4m3 h(f);
  return __builtin_bit_cast(u8, h);
}
__device__ __forceinline__ float fp82f(u8 u) {
  __hip_fp8_e4m3 h = __builtin_bit_cast(__hip_fp8_e4m3, u);
  return (float)h;
}

__device__ __forceinline__ void gload_lds16(const void* g, void* l) {
  __builtin_amdgcn_global_load_lds((const __attribute__((address_space(1))) void*)g,
                                   (__attribute__((address_space(3))) void*)l, 16, 0, 0);
}

// bf16 NT GEMM, fp8 out = acc*scale (weight-precontraction only; 512^3).
__global__ __launch_bounds__(256) void gemm_w(
    const u16* __restrict__ A, const u16* __restrict__ Bt, u8* __restrict__ OutV,
    int K, int lda, int ldb, int ldo, int GX, float scale) {
  __shared__ __align__(16) u16 lds_all[2 * 128 * BK];
  u16* As = lds_all;
  u16* Bs = lds_all + 128 * BK;

  const int gid = blockIdx.x;
  const int t0 = gid >> 3;  // 8 duplicate blocks per tile (benign identical writes)
  const int bx = t0 % GX;
  const int by = t0 / GX;
  const int tid = threadIdx.x;
  const int lane = tid & 63;
  const int wid = tid >> 6;
  const int wm = (wid >> 1) * 64;
  const int wn = (wid & 1) * 64;
  const int m0 = by * 128;
  const int n0 = bx * 128;
  const int l15 = lane & 15;
  const int lhi = lane >> 4;
  const int sw = l15 & 7;

  f32x4 acc[4][4];
#pragma unroll
  for (int i = 0; i < 4; ++i)
#pragma unroll
    for (int j = 0; j < 4; ++j) acc[i][j] = (f32x4){0.f, 0.f, 0.f, 0.f};

  for (int ks = 0; ks < K; ks += BK) {
#pragma unroll
    for (int i = 0; i < 4; ++i) {
      const int c = tid + i * 256;
      const int row = c >> 3;
      const int gslot = (c & 7) ^ (row & 7);
      gload_lds16(A + (long)(m0 + row) * lda + ks + gslot * 8, (void*)(As + c * 8));
    }
#pragma unroll
    for (int i = 0; i < 4; ++i) {
      const int c = tid + i * 256;
      const int row = c >> 3;
      const int gslot = (c & 7) ^ (row & 7);
      gload_lds16(Bt + (long)(n0 + row) * ldb + ks + gslot * 8, (void*)(Bs + c * 8));
    }
    __syncthreads();
#pragma unroll
    for (int kh = 0; kh < 2; ++kh) {
      short8 af[4], bf[4];
#pragma unroll
      for (int mf = 0; mf < 4; ++mf)
        af[mf] = *(const short8*)(As + (wm + mf * 16 + l15) * BK +
                                  ((kh * 4 + lhi) ^ sw) * 8);
#pragma unroll
      for (int nf = 0; nf < 4; ++nf)
        bf[nf] = *(const short8*)(Bs + (wn + nf * 16 + l15) * BK +
                                  ((kh * 4 + lhi) ^ sw) * 8);
#pragma unroll
      for (int mf = 0; mf < 4; ++mf)
#pragma unroll
        for (int nf = 0; nf < 4; ++nf)
          acc[mf][nf] = __builtin_amdgcn_mfma_f32_16x16x32_bf16(af[mf], bf[nf],
                                                                acc[mf][nf], 0, 0, 0);
    }
    __syncthreads();
  }

  const int rbase = m0 + wm + lhi * 4;
  const int cbase = n0 + wn + l15;
#pragma unroll
  for (int mf = 0; mf < 4; ++mf)
#pragma unroll
    for (int nf = 0; nf < 4; ++nf)
#pragma unroll
      for (int i = 0; i < 4; ++i)
        OutV[(long)(rbase + mf * 16 + i) * ldo + cbase + nf * 16] =
            f2fp8(acc[mf][nf][i] * scale);
}

// MX-scaled fp8 GEMM (m97 structure). K-tile = 128B rows; scale=1.0 pinned.
// MODE 2: fp8 out = exp(acc*scale); LDS rowsum reduce -> 1 atomicAdd/row
// MODE 4: f32 out = acc*scale + bias[row] + aux[b*sRes + row*ldo + col]
// MODE 5: fp8 out = acc / aux[b*sRes + row]
// MODE 6: fp8 out = acc*scale
template <int MODE>
__global__ __launch_bounds__(256) void gemm_mx(
    const u8* __restrict__ A, const u8* __restrict__ Bt, void* __restrict__ OutV,
    const float* __restrict__ bias, float* __restrict__ aux,
    int K, int lda, int ldb, int ldo, int GX, int mOffB,
    long sA, long sBt, long sOut, long sRes, float scale) {
  __shared__ __align__(16) u8 lds_all[2 * 128 * 128];  // 32 KB: As | Bs
  u8* As = lds_all;
  u8* Bs = lds_all + 128 * 128;

  const int gid = blockIdx.x;
  const int b = gid & 7;  // batch == XCD
  const int t0 = gid >> 3;
  const int bx = t0 % GX;
  const int by = t0 / GX;
  const u8* Ab = A + (long)b * sA;
  const u8* Bb = Bt + (long)b * sBt;
  const int tid = threadIdx.x;
  const int lane = tid & 63;
  const int wid = tid >> 6;
  const int wm = (wid >> 1) * 64;
  const int wn = (wid & 1) * 64;
  const int m0 = by * 128 + b * mOffB;
  const int n0 = bx * 128;
  const int l15 = lane & 15;
  const int lhi = lane >> 4;
  const int sw = l15 & 7;
  const int slo = ((2 * lhi) ^ sw) * 16;
  const int shi = ((2 * lhi + 1) ^ sw) * 16;

  f32x4 acc[4][4];
#pragma unroll
  for (int i = 0; i < 4; ++i)
#pragma unroll
    for (int j = 0; j < 4; ++j) acc[i][j] = (f32x4){0.f, 0.f, 0.f, 0.f};

  const int T = K / 128;
  for (int t = 0; t < T; ++t) {
    const int ks = t * 128;
#pragma unroll
    for (int i = 0; i < 4; ++i) {
      const int c = tid + i * 256;
      const int row = c >> 3;
      const int gslot = (c & 7) ^ (row & 7);
      gload_lds16(Ab + (long)(m0 + row) * lda + ks + gslot * 16, (void*)(As + c * 16));
    }
#pragma unroll
    for (int i = 0; i < 4; ++i) {
      const int c = tid + i * 256;
      const int row = c >> 3;
      const int gslot = (c & 7) ^ (row & 7);
      gload_lds16(Bb + (long)(n0 + row) * ldb + ks + gslot * 16, (void*)(Bs + c * 16));
    }
    __syncthreads();

    i32x8 af[4], bf[4];
#pragma unroll
    for (int mf = 0; mf < 4; ++mf) {
      const u8* base = As + (wm + mf * 16 + l15) * 128;
      const i32x4 lo = *(const i32x4*)(base + slo);
      const i32x4 hi = *(const i32x4*)(base + shi);
      af[mf][0] = lo[0]; af[mf][1] = lo[1]; af[mf][2] = lo[2]; af[mf][3] = lo[3];
      af[mf][4] = hi[0]; af[mf][5] = hi[1]; af[mf][6] = hi[2]; af[mf][7] = hi[3];
    }
#pragma unroll
    for (int nf = 0; nf < 4; ++nf) {
      const u8* base = Bs + (wn + nf * 16 + l15) * 128;
      const i32x4 lo = *(const i32x4*)(base + slo);
      const i32x4 hi = *(const i32x4*)(base + shi);
      bf[nf][0] = lo[0]; bf[nf][1] = lo[1]; bf[nf][2] = lo[2]; bf[nf][3] = lo[3];
      bf[nf][4] = hi[0]; bf[nf][5] = hi[1]; bf[nf][6] = hi[2]; bf[nf][7] = hi[3];
    }
#pragma unroll
    for (int mf = 0; mf < 4; ++mf)
#pragma unroll
      for (int nf = 0; nf < 4; ++nf)
        acc[mf][nf] = __builtin_amdgcn_mfma_scale_f32_16x16x128_f8f6f4(
            af[mf], bf[nf], acc[mf][nf], 0, 0, 0, 0x7F7F7F7F, 0, 0x7F7F7F7F);
    __syncthreads();
  }

  const int cbase = n0 + wn + l15;
  if constexpr (MODE == 2) {
    float* rs = (float*)lds_all;  // [128][33] floats (dead GEMM LDS)
#pragma unroll
    for (int mf = 0; mf < 4; ++mf) {
#pragma unroll
      for (int i = 0; i < 4; ++i) {
        const int rl = wm + mf * 16 + lhi * 4 + i;
        const int row = m0 + rl;
        float rsum = 0.f;
#pragma unroll
        for (int nf = 0; nf < 4; ++nf) {
          const int col = cbase + nf * 16;
          const long oidx = (long)b * sOut + (long)row * ldo + col;
          const u8 pe = f2fp8(__expf(acc[mf][nf][i] * scale));
          ((u8*)OutV)[oidx] = pe;
          rsum += fp82f(pe);  // sum what R will actually read
        }
        rs[rl * 33 + (wn >> 2) + l15] = rsum;
      }
    }
    __syncthreads();
    if (tid < 128) {
      float s = 0.f;
#pragma unroll
      for (int j = 0; j < 32; ++j) s += rs[tid * 33 + j];
      atomicAdd(&aux[(long)b * sRes + m0 + tid], s);
    }
  } else {
    const int rbase = m0 + wm + lhi * 4;
#pragma unroll
    for (int mf = 0; mf < 4; ++mf) {
#pragma unroll
      for (int nf = 0; nf < 4; ++nf) {
#pragma unroll
        for (int i = 0; i < 4; ++i) {
          const int row = rbase + mf * 16 + i;
          const int col = cbase + nf * 16;
          const long oidx = (long)b * sOut + (long)row * ldo + col;
          const float v = acc[mf][nf][i];
          if (MODE == 5) {
            ((u8*)OutV)[oidx] = f2fp8(v / aux[(long)b * sRes + row]);
          } else if (MODE == 6) {
            ((u8*)OutV)[oidx] = f2fp8(v * scale);
          } else {  // MODE 4
            const float r = aux[(long)b * sRes + (long)row * ldo + col];
            ((float*)OutV)[oidx] = v * scale + bias[row] + r;
          }
        }
      }
    }
  }
}

// Single-pass register-resident GroupNorm -> fp8 hT (transposed) + fp8 h (natural).
__global__ __launch_bounds__(256) void gn_reg(
    const float* __restrict__ x, const float* __restrict__ gamma,
    const float* __restrict__ beta, u8* __restrict__ hT8, u8* __restrict__ h8) {
  const int gid = blockIdx.x;
  const int b = gid & 7;
  const int g = gid >> 3;
  const float* px = x + ((long)b * 512 + g * 16) * 2048;
  const int tid = threadIdx.x;
  const int lane = tid & 63, wid = tid >> 6;

  u32 pk[64];
  float s = 0.f, ss = 0.f;
#pragma unroll
  for (int j = 0; j < 32; ++j) {
    const float4 u = ((const float4*)px)[tid + 256 * j];
    s += (u.x + u.y) + (u.z + u.w);
    ss += (u.x * u.x + u.y * u.y) + (u.z * u.z + u.w * u.w);
    pk[2 * j] = (u32)f2bf(u.x) | ((u32)f2bf(u.y) << 16);
    pk[2 * j + 1] = (u32)f2bf(u.z) | ((u32)f2bf(u.w) << 16);
  }
#pragma unroll
  for (int off = 32; off > 0; off >>= 1) {
    s += __shfl_xor(s, off, 64);
    ss += __shfl_xor(ss, off, 64);
  }
  __shared__ float rs4[4], rss4[4], ga[16], be[16];
  if (lane == 0) { rs4[wid] = s; rss4[wid] = ss; }
  __syncthreads();
  if (tid == 0) {
    s = rs4[0] + rs4[1] + rs4[2] + rs4[3];
    ss = rss4[0] + rss4[1] + rss4[2] + rss4[3];
    const float mean = s * (1.f / 32768.f);
    const float var = ss * (1.f / 32768.f) - mean * mean;
    rs4[0] = mean;
    rss4[0] = rsqrtf(var + 1e-6f);
  }
  __syncthreads();
  if (tid < 16) {
    const float gaa = gamma[g * 16 + tid] * rss4[0];
    ga[tid] = gaa;
    be[tid] = beta[g * 16 + tid] - rs4[0] * gaa;
  }
  __syncthreads();

  float gar[16], ber[16];
#pragma unroll
  for (int c = 0; c < 16; ++c) { gar[c] = ga[c]; ber[c] = be[c]; }

  // hT8 rows n = 4t+r (+1024p): 16 channels = one 16B store per row
#pragma unroll
  for (int p = 0; p < 2; ++p) {
#pragma unroll
    for (int r = 0; r < 4; ++r) {
      const int n = 4 * tid + r + 1024 * p;
      u8 w[16];
#pragma unroll
      for (int c = 0; c < 16; ++c) {
        const u32 word = pk[2 * (2 * c + p) + (r >> 1)];
        const float xv = bf2f((u16)(word >> (16 * (r & 1))));
        w[c] = f2fp8(xv * gar[c] + ber[c]);
      }
      *(i32x4*)(hT8 + ((long)b * 2048 + n) * 512 + g * 16) = *(i32x4*)&w[0];
    }
  }
  // h8 natural: per (c,p) one 4-byte store of the 4 n-values
#pragma unroll
  for (int p = 0; p < 2; ++p) {
#pragma unroll
    for (int c = 0; c < 16; ++c) {
      const u32 w0 = pk[2 * (2 * c + p)];
      const u32 w1 = pk[2 * (2 * c + p) + 1];
      u8 q[4];
      q[0] = f2fp8(bf2f((u16)w0) * gar[c] + ber[c]);
      q[1] = f2fp8(bf2f((u16)(w0 >> 16)) * gar[c] + ber[c]);
      q[2] = f2fp8(bf2f((u16)w1) * gar[c] + ber[c]);
      q[3] = f2fp8(bf2f((u16)(w1 >> 16)) * gar[c] + ber[c]);
      *(u32*)(h8 + ((long)b * 512 + g * 16 + c) * 2048 + 1024 * p + 4 * tid) = *(u32*)q;
    }
  }
}

// transposed bf16 weights (WqT|WkT|WvT) + natural Wp16; z==3 also zeroes rowsum
__global__ __launch_bounds__(256) void cvt_w(const float* __restrict__ wq,
                                             const float* __restrict__ wk,
                                             const float* __restrict__ wv,
                                             const float* __restrict__ wp,
                                             float* __restrict__ rowsum,
                                             u16* __restrict__ wqT,
                                             u16* __restrict__ wkT,
                                             u16* __restrict__ wvT,
                                             u16* __restrict__ wp16) {
  const int z = blockIdx.y;
  const int i = blockIdx.x * 256 + threadIdx.x;  // 262144
  const int r = i >> 9, c = i & 511;
  if (z == 0) {
    wqT[c * 512 + r] = f2bf(wq[i]);
  } else if (z == 1) {
    wkT[c * 512 + r] = f2bf(wk[i]);
  } else if (z == 2) {
    wvT[c * 512 + r] = f2bf(wv[i]);
  } else {
    wp16[i] = f2bf(wp[i]);
    if (i < 16384) rowsum[i] = 0.f;
  }
}

// obias[o] = bp[o] + sum_c wp[o][c]*bv[c]
__global__ __launch_bounds__(256) void obias_k(const float* __restrict__ wp,
                                               const float* __restrict__ bv,
                                               const float* __restrict__ bp,
                                               float* __restrict__ obias) {
  const int o = blockIdx.x * 256 + threadIdx.x;
  float s = bp[o];
  for (int c = 0; c < 512; ++c) s += wp[o * 512 + c] * bv[c];
  obias[o] = s;
}

extern "C" void kernel_launch(void* const* d_in, const int* in_sizes, int n_in,
                              void* d_out, int out_size, void* d_ws, size_t ws_size,
                              hipStream_t stream) {
  const float* x = (const float*)d_in[0];
  const float* gs = (const float*)d_in[1];
  const float* gb = (const float*)d_in[2];
  const float* wq = (const float*)d_in[3];
  const float* bv = (const float*)d_in[8];
  const float* wk = (const float*)d_in[5];
  const float* wv = (const float*)d_in[7];
  const float* wp = (const float*)d_in[9];
  const float* bp = (const float*)d_in[10];

  char* ws = (char*)d_ws;
  float* rowsum = (float*)(ws + 12288);    // 64 KB [B*2048]
  float* obias = (float*)(ws + 81920);     // 2 KB
  u8* hT8 = (u8*)(ws + 131072);            // [16384, 512] fp8, 8 MB
  u8* h8 = hT8 + 8388608;                  // [B, 512, 2048] fp8, 8 MB
  u8* q8 = h8 + 8388608;                   // [16384, 512] fp8, 8 MB
  u8* S8 = q8 + 8388608;                   // [B, 2048, 2048] fp8, 32 MB (holds P)
  u8* R8 = S8 + 33554432;                  // [16384, 512] fp8, 8 MB
  u16* wqT = (u16*)(R8 + 8388608);         // 512 KB
  u16* wkT = wqT + 262144;                 // 512 KB
  u16* wvT = wkT + 262144;                 // 512 KB
  u16* wp16 = wvT + 262144;                // 512 KB
  u8* MqkT8 = (u8*)(wp16 + 262144);        // [512,512] fp8, 256 KB
  u8* Mpv8 = MqkT8 + 262144;               // [512,512] fp8, 256 KB
  float* out = (float*)d_out;

  cvt_w<<<dim3(1024, 4, 1), 256, 0, stream>>>(wq, wk, wv, wp, rowsum,
                                              wqT, wkT, wvT, wp16);
  obias_k<<<dim3(2), 256, 0, stream>>>(wp, bv, bp, obias);
  gn_reg<<<dim3(256), 256, 0, stream>>>(x, gs, gb, hT8, h8);

  // MqkT8[d][c] = fp8(16 * sum_c' Wk[c'][d]*Wq[c'][c]): A=WkT, Bt=WqT
  gemm_w<<<dim3(128), 256, 0, stream>>>(wkT, wqT, MqkT8, 512, 512, 512, 512, 4, 16.f);
  // Mpv8[o][d] = fp8(16 * sum_c Wp[o][c]*Wv[c][d]): A=Wp16, Bt=WvT
  gemm_w<<<dim3(128), 256, 0, stream>>>(wp16, wvT, Mpv8, 512, 512, 512, 512, 4, 16.f);

  // q' = hT * MqkT: M=16384 (mOffB=2048, sOut=0 -> flat rows), N=512; 512 blocks
  gemm_mx<6><<<dim3(512), 256, 0, stream>>>(
      hT8, MqkT8, q8, nullptr, nullptr, 512, 512, 512, 512, 4, 2048,
      0, 0, 0, 0, 1.f);
  // S: batch via sA/sBt (mOffB=0!), M=2048/b, N=2048, K=512; exp + rowsum
  gemm_mx<2><<<dim3(2048), 256, 0, stream>>>(
      q8, hT8, S8, nullptr, rowsum, 512, 512, 512, 2048, 16, 0,
      1048576, 1048576, 4194304, 2048, 0.04419417382415922f / 16.f);
  // R = P * h8: M=2048, N=512, K=2048; epilogue / rowsum -> fp8; 512 blocks
  gemm_mx<5><<<dim3(512), 256, 0, stream>>>(
      S8, h8, R8, nullptr, rowsum, 2048, 2048, 2048, 512, 4, 0,
      4194304, 1048576, 1048576, 2048, 0.f);
  // out = (Mpv8 . R8)/16 + obias[row] + x: M=512, N=2048, K=512; 512 blocks
  gemm_mx<4><<<dim3(512), 256, 0, stream>>>(
      Mpv8, R8, out, obias, (float*)x, 512, 512, 512, 2048, 16, 0,
      0, 1048576, 1048576, 1048576, 1.f / 16.f);
}

// Round 26
// 117.357 us; speedup vs baseline: 1.2042x; 1.2042x over previous
//
#include <hip/hip_runtime.h>
#include <hip/hip_bf16.h>
#include <hip/hip_fp8.h>

// AttnBlock: B=8, C=512, N=2048, G=32.
// R26 = R25 (141us, correct algebra, slow preamble) with the preamble fixed:
//   - trans_w: LDS-tiled 64x64 transpose fp32->bf16 (coalesced both sides) for
//     wq,wk,wv  (R25 did scattered stride-1024B u16 stores);
//   - wp_cvt: flat vectorized wp->bf16 + rowsum zero;
//   - obias_k: 512 blocks, coalesced row read + wave reduce (R25: 2 blocks,
//     serial uncoalesced loops);
//   - gemm_w: ONE launch, grid (16,2), no duplicate blocks.
// Algebra + main pipeline byte-identical to R25: k/v projections eliminated,
//   q' = hT*MqkT (x16 fp8), S = exp(q'*hT^T * scale/16)+rowsum, R = P*h /rowsum,
//   out = (Mpv.R)/16 + obias + x. m97 128x128 MX core, T2 swizzle, XCD pinning.

typedef __attribute__((ext_vector_type(8))) short short8;
typedef __attribute__((ext_vector_type(4))) float f32x4;
typedef __attribute__((ext_vector_type(8))) int i32x8;
typedef __attribute__((ext_vector_type(4))) int i32x4;
typedef unsigned short u16;
typedef unsigned char u8;
typedef unsigned int u32;

#define BK 64

__device__ __forceinline__ u16 f2bf(float f) {
  __hip_bfloat16 h = __float2bfloat16(f);
  return __builtin_bit_cast(u16, h);
}
__device__ __forceinline__ float bf2f(u16 u) {
  return __uint_as_float(((u32)u) << 16);
}
__device__ __forceinline__ u8 f2fp8(float f) {
  __hip_fp8_e4m3 h(f);
  return __builtin_bit_cast(u8, h);
}
__device__ __forceinline__ float fp82f(u8 u) {
  __hip_fp8_e4m3 h = __builtin_bit_cast(__hip_fp8_e4m3, u);
  return (float)h;
}

__device__ __forceinline__ void gload_lds16(const void* g, void* l) {
  __builtin_amdgcn_global_load_lds((const __attribute__((address_space(1))) void*)g,
                                   (__attribute__((address_space(3))) void*)l, 16, 0, 0);
}

// bf16 NT GEMM, fp8 out = acc*scale (weight precontraction; grid (16,2)).
__global__ __launch_bounds__(256) void gemm_w(
    const u16* __restrict__ A0, const u16* __restrict__ Bt0, u8* __restrict__ Out0,
    const u16* __restrict__ A1, const u16* __restrict__ Bt1, u8* __restrict__ Out1,
    float scale) {
  const u16* A = blockIdx.y ? A1 : A0;
  const u16* Bt = blockIdx.y ? Bt1 : Bt0;
  u8* OutV = blockIdx.y ? Out1 : Out0;

  __shared__ __align__(16) u16 lds_all[2 * 128 * BK];
  u16* As = lds_all;
  u16* Bs = lds_all + 128 * BK;

  const int bx = blockIdx.x & 3;
  const int by = blockIdx.x >> 2;
  const int tid = threadIdx.x;
  const int lane = tid & 63;
  const int wid = tid >> 6;
  const int wm = (wid >> 1) * 64;
  const int wn = (wid & 1) * 64;
  const int m0 = by * 128;
  const int n0 = bx * 128;
  const int l15 = lane & 15;
  const int lhi = lane >> 4;
  const int sw = l15 & 7;

  f32x4 acc[4][4];
#pragma unroll
  for (int i = 0; i < 4; ++i)
#pragma unroll
    for (int j = 0; j < 4; ++j) acc[i][j] = (f32x4){0.f, 0.f, 0.f, 0.f};

  for (int ks = 0; ks < 512; ks += BK) {
#pragma unroll
    for (int i = 0; i < 4; ++i) {
      const int c = tid + i * 256;
      const int row = c >> 3;
      const int gslot = (c & 7) ^ (row & 7);
      gload_lds16(A + (long)(m0 + row) * 512 + ks + gslot * 8, (void*)(As + c * 8));
    }
#pragma unroll
    for (int i = 0; i < 4; ++i) {
      const int c = tid + i * 256;
      const int row = c >> 3;
      const int gslot = (c & 7) ^ (row & 7);
      gload_lds16(Bt + (long)(n0 + row) * 512 + ks + gslot * 8, (void*)(Bs + c * 8));
    }
    __syncthreads();
#pragma unroll
    for (int kh = 0; kh < 2; ++kh) {
      short8 af[4], bf[4];
#pragma unroll
      for (int mf = 0; mf < 4; ++mf)
        af[mf] = *(const short8*)(As + (wm + mf * 16 + l15) * BK +
                                  ((kh * 4 + lhi) ^ sw) * 8);
#pragma unroll
      for (int nf = 0; nf < 4; ++nf)
        bf[nf] = *(const short8*)(Bs + (wn + nf * 16 + l15) * BK +
                                  ((kh * 4 + lhi) ^ sw) * 8);
#pragma unroll
      for (int mf = 0; mf < 4; ++mf)
#pragma unroll
        for (int nf = 0; nf < 4; ++nf)
          acc[mf][nf] = __builtin_amdgcn_mfma_f32_16x16x32_bf16(af[mf], bf[nf],
                                                                acc[mf][nf], 0, 0, 0);
    }
    __syncthreads();
  }

  const int rbase = m0 + wm + lhi * 4;
  const int cbase = n0 + wn + l15;
#pragma unroll
  for (int mf = 0; mf < 4; ++mf)
#pragma unroll
    for (int nf = 0; nf < 4; ++nf)
#pragma unroll
      for (int i = 0; i < 4; ++i)
        OutV[(long)(rbase + mf * 16 + i) * 512 + cbase + nf * 16] =
            f2fp8(acc[mf][nf][i] * scale);
}

// MX-scaled fp8 GEMM (m97 structure). K-tile = 128B rows; scale=1.0 pinned.
// MODE 2: fp8 out = exp(acc*scale); LDS rowsum reduce -> 1 atomicAdd/row
// MODE 4: f32 out = acc*scale + bias[row] + aux[b*sRes + row*ldo + col]
// MODE 5: fp8 out = acc / aux[b*sRes + row]
// MODE 6: fp8 out = acc*scale
template <int MODE>
__global__ __launch_bounds__(256) void gemm_mx(
    const u8* __restrict__ A, const u8* __restrict__ Bt, void* __restrict__ OutV,
    const float* __restrict__ bias, float* __restrict__ aux,
    int K, int lda, int ldb, int ldo, int GX, int mOffB,
    long sA, long sBt, long sOut, long sRes, float scale) {
  __shared__ __align__(16) u8 lds_all[2 * 128 * 128];  // 32 KB: As | Bs
  u8* As = lds_all;
  u8* Bs = lds_all + 128 * 128;

  const int gid = blockIdx.x;
  const int b = gid & 7;  // batch == XCD
  const int t0 = gid >> 3;
  const int bx = t0 % GX;
  const int by = t0 / GX;
  const u8* Ab = A + (long)b * sA;
  const u8* Bb = Bt + (long)b * sBt;
  const int tid = threadIdx.x;
  const int lane = tid & 63;
  const int wid = tid >> 6;
  const int wm = (wid >> 1) * 64;
  const int wn = (wid & 1) * 64;
  const int m0 = by * 128 + b * mOffB;
  const int n0 = bx * 128;
  const int l15 = lane & 15;
  const int lhi = lane >> 4;
  const int sw = l15 & 7;
  const int slo = ((2 * lhi) ^ sw) * 16;
  const int shi = ((2 * lhi + 1) ^ sw) * 16;

  f32x4 acc[4][4];
#pragma unroll
  for (int i = 0; i < 4; ++i)
#pragma unroll
    for (int j = 0; j < 4; ++j) acc[i][j] = (f32x4){0.f, 0.f, 0.f, 0.f};

  const int T = K / 128;
  for (int t = 0; t < T; ++t) {
    const int ks = t * 128;
#pragma unroll
    for (int i = 0; i < 4; ++i) {
      const int c = tid + i * 256;
      const int row = c >> 3;
      const int gslot = (c & 7) ^ (row & 7);
      gload_lds16(Ab + (long)(m0 + row) * lda + ks + gslot * 16, (void*)(As + c * 16));
    }
#pragma unroll
    for (int i = 0; i < 4; ++i) {
      const int c = tid + i * 256;
      const int row = c >> 3;
      const int gslot = (c & 7) ^ (row & 7);
      gload_lds16(Bb + (long)(n0 + row) * ldb + ks + gslot * 16, (void*)(Bs + c * 16));
    }
    __syncthreads();

    i32x8 af[4], bf[4];
#pragma unroll
    for (int mf = 0; mf < 4; ++mf) {
      const u8* base = As + (wm + mf * 16 + l15) * 128;
      const i32x4 lo = *(const i32x4*)(base + slo);
      const i32x4 hi = *(const i32x4*)(base + shi);
      af[mf][0] = lo[0]; af[mf][1] = lo[1]; af[mf][2] = lo[2]; af[mf][3] = lo[3];
      af[mf][4] = hi[0]; af[mf][5] = hi[1]; af[mf][6] = hi[2]; af[mf][7] = hi[3];
    }
#pragma unroll
    for (int nf = 0; nf < 4; ++nf) {
      const u8* base = Bs + (wn + nf * 16 + l15) * 128;
      const i32x4 lo = *(const i32x4*)(base + slo);
      const i32x4 hi = *(const i32x4*)(base + shi);
      bf[nf][0] = lo[0]; bf[nf][1] = lo[1]; bf[nf][2] = lo[2]; bf[nf][3] = lo[3];
      bf[nf][4] = hi[0]; bf[nf][5] = hi[1]; bf[nf][6] = hi[2]; bf[nf][7] = hi[3];
    }
#pragma unroll
    for (int mf = 0; mf < 4; ++mf)
#pragma unroll
      for (int nf = 0; nf < 4; ++nf)
        acc[mf][nf] = __builtin_amdgcn_mfma_scale_f32_16x16x128_f8f6f4(
            af[mf], bf[nf], acc[mf][nf], 0, 0, 0, 0x7F7F7F7F, 0, 0x7F7F7F7F);
    __syncthreads();
  }

  const int cbase = n0 + wn + l15;
  if constexpr (MODE == 2) {
    float* rs = (float*)lds_all;  // [128][33] floats (dead GEMM LDS)
#pragma unroll
    for (int mf = 0; mf < 4; ++mf) {
#pragma unroll
      for (int i = 0; i < 4; ++i) {
        const int rl = wm + mf * 16 + lhi * 4 + i;
        const int row = m0 + rl;
        float rsum = 0.f;
#pragma unroll
        for (int nf = 0; nf < 4; ++nf) {
          const int col = cbase + nf * 16;
          const long oidx = (long)b * sOut + (long)row * ldo + col;
          const u8 pe = f2fp8(__expf(acc[mf][nf][i] * scale));
          ((u8*)OutV)[oidx] = pe;
          rsum += fp82f(pe);  // sum what R will actually read
        }
        rs[rl * 33 + (wn >> 2) + l15] = rsum;
      }
    }
    __syncthreads();
    if (tid < 128) {
      float s = 0.f;
#pragma unroll
      for (int j = 0; j < 32; ++j) s += rs[tid * 33 + j];
      atomicAdd(&aux[(long)b * sRes + m0 + tid], s);
    }
  } else {
    const int rbase = m0 + wm + lhi * 4;
#pragma unroll
    for (int mf = 0; mf < 4; ++mf) {
#pragma unroll
      for (int nf = 0; nf < 4; ++nf) {
#pragma unroll
        for (int i = 0; i < 4; ++i) {
          const int row = rbase + mf * 16 + i;
          const int col = cbase + nf * 16;
          const long oidx = (long)b * sOut + (long)row * ldo + col;
          const float v = acc[mf][nf][i];
          if (MODE == 5) {
            ((u8*)OutV)[oidx] = f2fp8(v / aux[(long)b * sRes + row]);
          } else if (MODE == 6) {
            ((u8*)OutV)[oidx] = f2fp8(v * scale);
          } else {  // MODE 4
            const float r = aux[(long)b * sRes + (long)row * ldo + col];
            ((float*)OutV)[oidx] = v * scale + bias[row] + r;
          }
        }
      }
    }
  }
}

// Single-pass register-resident GroupNorm -> fp8 hT (transposed) + fp8 h (natural).
__global__ __launch_bounds__(256) void gn_reg(
    const float* __restrict__ x, const float* __restrict__ gamma,
    const float* __restrict__ beta, u8* __restrict__ hT8, u8* __restrict__ h8) {
  const int gid = blockIdx.x;
  const int b = gid & 7;
  const int g = gid >> 3;
  const float* px = x + ((long)b * 512 + g * 16) * 2048;
  const int tid = threadIdx.x;
  const int lane = tid & 63, wid = tid >> 6;

  u32 pk[64];
  float s = 0.f, ss = 0.f;
#pragma unroll
  for (int j = 0; j < 32; ++j) {
    const float4 u = ((const float4*)px)[tid + 256 * j];
    s += (u.x + u.y) + (u.z + u.w);
    ss += (u.x * u.x + u.y * u.y) + (u.z * u.z + u.w * u.w);
    pk[2 * j] = (u32)f2bf(u.x) | ((u32)f2bf(u.y) << 16);
    pk[2 * j + 1] = (u32)f2bf(u.z) | ((u32)f2bf(u.w) << 16);
  }
#pragma unroll
  for (int off = 32; off > 0; off >>= 1) {
    s += __shfl_xor(s, off, 64);
    ss += __shfl_xor(ss, off, 64);
  }
  __shared__ float rs4[4], rss4[4], ga[16], be[16];
  if (lane == 0) { rs4[wid] = s; rss4[wid] = ss; }
  __syncthreads();
  if (tid == 0) {
    s = rs4[0] + rs4[1] + rs4[2] + rs4[3];
    ss = rss4[0] + rss4[1] + rss4[2] + rss4[3];
    const float mean = s * (1.f / 32768.f);
    const float var = ss * (1.f / 32768.f) - mean * mean;
    rs4[0] = mean;
    rss4[0] = rsqrtf(var + 1e-6f);
  }
  __syncthreads();
  if (tid < 16) {
    const float gaa = gamma[g * 16 + tid] * rss4[0];
    ga[tid] = gaa;
    be[tid] = beta[g * 16 + tid] - rs4[0] * gaa;
  }
  __syncthreads();

  float gar[16], ber[16];
#pragma unroll
  for (int c = 0; c < 16; ++c) { gar[c] = ga[c]; ber[c] = be[c]; }

#pragma unroll
  for (int p = 0; p < 2; ++p) {
#pragma unroll
    for (int r = 0; r < 4; ++r) {
      const int n = 4 * tid + r + 1024 * p;
      u8 w[16];
#pragma unroll
      for (int c = 0; c < 16; ++c) {
        const u32 word = pk[2 * (2 * c + p) + (r >> 1)];
        const float xv = bf2f((u16)(word >> (16 * (r & 1))));
        w[c] = f2fp8(xv * gar[c] + ber[c]);
      }
      *(i32x4*)(hT8 + ((long)b * 2048 + n) * 512 + g * 16) = *(i32x4*)&w[0];
    }
  }
#pragma unroll
  for (int p = 0; p < 2; ++p) {
#pragma unroll
    for (int c = 0; c < 16; ++c) {
      const u32 w0 = pk[2 * (2 * c + p)];
      const u32 w1 = pk[2 * (2 * c + p) + 1];
      u8 q[4];
      q[0] = f2fp8(bf2f((u16)w0) * gar[c] + ber[c]);
      q[1] = f2fp8(bf2f((u16)(w0 >> 16)) * gar[c] + ber[c]);
      q[2] = f2fp8(bf2f((u16)w1) * gar[c] + ber[c]);
      q[3] = f2fp8(bf2f((u16)(w1 >> 16)) * gar[c] + ber[c]);
      *(u32*)(h8 + ((long)b * 512 + g * 16 + c) * 2048 + 1024 * p + 4 * tid) = *(u32*)q;
    }
  }
}

// LDS-tiled transpose fp32 -> bf16: dst[c][r] = src[r][c].  512x512, 64x64 tiles.
// grid (8, 8, 3): z selects wq/wk/wv.
__global__ __launch_bounds__(256) void trans_w(const float* __restrict__ w0,
                                               const float* __restrict__ w1,
                                               const float* __restrict__ w2,
                                               u16* __restrict__ t0,
                                               u16* __restrict__ t1,
                                               u16* __restrict__ t2) {
  const float* src = (blockIdx.z == 0) ? w0 : (blockIdx.z == 1) ? w1 : w2;
  u16* dst = (blockIdx.z == 0) ? t0 : (blockIdx.z == 1) ? t1 : t2;
  const int r0 = blockIdx.y * 64, c0 = blockIdx.x * 64;
  __shared__ u16 t[64][72];
  const int tid = threadIdx.x;
#pragma unroll
  for (int i = 0; i < 4; ++i) {
    const int idx = tid + i * 256;          // 1024 float4 = 64 rows x 16
    const int rr = idx >> 4, cq = (idx & 15) * 4;
    const float4 u = *(const float4*)(src + (long)(r0 + rr) * 512 + c0 + cq);
    t[rr][cq + 0] = f2bf(u.x);
    t[rr][cq + 1] = f2bf(u.y);
    t[rr][cq + 2] = f2bf(u.z);
    t[rr][cq + 3] = f2bf(u.w);
  }
  __syncthreads();
#pragma unroll
  for (int i = 0; i < 2; ++i) {
    const int idx = tid + i * 256;          // 512 chunks = 64 c-rows x 8
    const int cc = idx >> 3, rq = (idx & 7) * 8;
    short8 w;
#pragma unroll
    for (int j = 0; j < 8; ++j) w[j] = (short)t[rq + j][cc];
    *(short8*)(dst + (long)(c0 + cc) * 512 + r0 + rq) = w;
  }
}

// wp -> bf16 (flat, vectorized) + rowsum zero.  grid 256.
__global__ __launch_bounds__(256) void wp_cvt(const float* __restrict__ wp,
                                              u16* __restrict__ wp16,
                                              float* __restrict__ rowsum) {
  const int i = blockIdx.x * 256 + threadIdx.x;  // f32x4 index, 65536 total
  const float4 u = ((const float4*)wp)[i];
  ushort4 o;
  o.x = f2bf(u.x); o.y = f2bf(u.y); o.z = f2bf(u.z); o.w = f2bf(u.w);
  *(ushort4*)(wp16 + i * 4) = o;
  if (i < 16384) rowsum[i] = 0.f;
}

// obias[o] = bp[o] + sum_c wp[o][c]*bv[c].  One block per o, coalesced row read.
__global__ __launch_bounds__(256) void obias_k(const float* __restrict__ wp,
                                               const float* __restrict__ bv,
                                               const float* __restrict__ bp,
                                               float* __restrict__ obias) {
  const int o = blockIdx.x;
  const int tid = threadIdx.x;
  float s = wp[o * 512 + tid] * bv[tid] + wp[o * 512 + 256 + tid] * bv[256 + tid];
#pragma unroll
  for (int off = 32; off > 0; off >>= 1) s += __shfl_xor(s, off, 64);
  __shared__ float rs[4];
  if ((tid & 63) == 0) rs[tid >> 6] = s;
  __syncthreads();
  if (tid == 0) obias[o] = bp[o] + rs[0] + rs[1] + rs[2] + rs[3];
}

extern "C" void kernel_launch(void* const* d_in, const int* in_sizes, int n_in,
                              void* d_out, int out_size, void* d_ws, size_t ws_size,
                              hipStream_t stream) {
  const float* x = (const float*)d_in[0];
  const float* gs = (const float*)d_in[1];
  const float* gb = (const float*)d_in[2];
  const float* wq = (const float*)d_in[3];
  const float* wk = (const float*)d_in[5];
  const float* wv = (const float*)d_in[7];
  const float* bv = (const float*)d_in[8];
  const float* wp = (const float*)d_in[9];
  const float* bp = (const float*)d_in[10];

  char* ws = (char*)d_ws;
  float* rowsum = (float*)(ws + 12288);    // 64 KB [B*2048]
  float* obias = (float*)(ws + 81920);     // 2 KB
  u8* hT8 = (u8*)(ws + 131072);            // [16384, 512] fp8, 8 MB
  u8* h8 = hT8 + 8388608;                  // [B, 512, 2048] fp8, 8 MB
  u8* q8 = h8 + 8388608;                   // [16384, 512] fp8, 8 MB
  u8* S8 = q8 + 8388608;                   // [B, 2048, 2048] fp8, 32 MB (holds P)
  u8* R8 = S8 + 33554432;                  // [16384, 512] fp8, 8 MB
  u16* wqT = (u16*)(R8 + 8388608);         // 512 KB
  u16* wkT = wqT + 262144;                 // 512 KB
  u16* wvT = wkT + 262144;                 // 512 KB
  u16* wp16 = wvT + 262144;                // 512 KB
  u8* MqkT8 = (u8*)(wp16 + 262144);        // [512,512] fp8, 256 KB
  u8* Mpv8 = MqkT8 + 262144;               // [512,512] fp8, 256 KB
  float* out = (float*)d_out;

  trans_w<<<dim3(8, 8, 3), 256, 0, stream>>>(wq, wk, wv, wqT, wkT, wvT);
  wp_cvt<<<dim3(256), 256, 0, stream>>>(wp, wp16, rowsum);
  obias_k<<<dim3(512), 256, 0, stream>>>(wp, bv, bp, obias);
  // y=0: MqkT8[d][c] = fp8(16 * sum_e Wk[e][d]*Wq[e][c]) (A=WkT, Bt=WqT)
  // y=1: Mpv8[o][d]  = fp8(16 * sum_c Wp[o][c]*Wv[c][d]) (A=Wp16, Bt=WvT)
  gemm_w<<<dim3(16, 2), 256, 0, stream>>>(wkT, wqT, MqkT8, wp16, wvT, Mpv8, 16.f);
  gn_reg<<<dim3(256), 256, 0, stream>>>(x, gs, gb, hT8, h8);

  // q' = hT * MqkT: M=16384 (mOffB=2048, sOut=0 -> flat rows), N=512; 512 blocks
  gemm_mx<6><<<dim3(512), 256, 0, stream>>>(
      hT8, MqkT8, q8, nullptr, nullptr, 512, 512, 512, 512, 4, 2048,
      0, 0, 0, 0, 1.f);
  // S: batch via sA/sBt (mOffB=0), M=2048/b, N=2048, K=512; exp + rowsum
  gemm_mx<2><<<dim3(2048), 256, 0, stream>>>(
      q8, hT8, S8, nullptr, rowsum, 512, 512, 512, 2048, 16, 0,
      1048576, 1048576, 4194304, 2048, 0.04419417382415922f / 16.f);
  // R = P * h8: M=2048, N=512, K=2048; epilogue / rowsum -> fp8; 512 blocks
  gemm_mx<5><<<dim3(512), 256, 0, stream>>>(
      S8, h8, R8, nullptr, rowsum, 2048, 2048, 2048, 512, 4, 0,
      4194304, 1048576, 1048576, 2048, 0.f);
  // out = (Mpv8 . R8)/16 + obias[row] + x: M=512, N=2048, K=512; 512 blocks
  gemm_mx<4><<<dim3(512), 256, 0, stream>>>(
      Mpv8, R8, out, obias, (float*)x, 512, 512, 512, 2048, 16, 0,
      0, 1048576, 1048576, 1048576, 1.f / 16.f);
}